// Round 8
// baseline (715.802 us; speedup 1.0000x reference)
//
#include <hip/hip_runtime.h>
#include <math.h>

// ---------------------------------------------------------------------------
// Round 8: r7 double-buffered single-barrier K-loop, but 512-thread blocks
// (8 waves, 4x2 wave grid, each wave 32x64 via 2x4 accs) on the same 128x128
// tile -> 2x waves/CU for latency hiding (chain: 24 waves/CU, W_map: 16).
// Gate-interleave preserved: wc picks the 64-col gate group. Grid n-fastest.
// ---------------------------------------------------------------------------

using bf16x8 = __attribute__((ext_vector_type(8))) short;
using f32x4  = __attribute__((ext_vector_type(4))) float;

enum { EPI_NONE = 0, EPI_RELU = 1, EPI_TANH = 2 };

__device__ inline unsigned short f2bf(float f) {
    union { float f; unsigned u; } v; v.f = f;
    unsigned r = v.u + 0x7FFFu + ((v.u >> 16) & 1u);
    return (unsigned short)(r >> 16);
}
__device__ inline float sigf(float x) {
    return __fdividef(1.f, 1.f + __expf(-x));
}
__device__ inline float tanhfast(float x) {
    return 1.f - __fdividef(2.f, 1.f + __expf(2.f * x));
}

__device__ inline void gll16(const void* g, void* l) {
    __builtin_amdgcn_global_load_lds(
        (const __attribute__((address_space(1))) unsigned int*)(uintptr_t)g,
        (__attribute__((address_space(3))) unsigned int*)(unsigned int)(uintptr_t)l,
        16, 0, 0);
}

// stage one 128x32 A-tile + B-tile into buffer b_ (async; 1 chunk/thread)
#define STAGE(A_, Bt_, K_, k0_, b_)                                            \
    {                                                                          \
        const int row = tid >> 2, kc = tid & 3;                                \
        gll16((A_)  + (size_t)(m0 + row) * (K_) + (k0_) + kc * 8,              \
              (void*)&As[b_][tid * 8]);                                        \
        gll16((Bt_) + (size_t)(n0 + row) * (K_) + (k0_) + kc * 8,              \
              (void*)&Bs[b_][tid * 8]);                                        \
    }

// double-buffered K-loop: one barrier/iter, vmcnt drain overlapped with MFMA
#define GEMM_CORE(A_, Bt_, K_)                                                 \
    STAGE(A_, Bt_, K_, 0, 0)                                                   \
    {                                                                          \
        const int niter = (K_) / 32;                                           \
        for (int it = 0; it < niter; ++it) {                                   \
            __syncthreads();                                                   \
            if (it + 1 < niter) {                                              \
                const int kn = (it + 1) * 32, bn = (it + 1) & 1;               \
                STAGE(A_, Bt_, K_, kn, bn)                                     \
            }                                                                  \
            const unsigned short* Asb = As[it & 1];                            \
            const unsigned short* Bsb = Bs[it & 1];                            \
            bf16x8 aF[2], bF[4];                                               \
            _Pragma("unroll")                                                  \
            for (int mi = 0; mi < 2; ++mi)                                     \
                aF[mi] = *(const bf16x8*)(Asb + (wr*32 + mi*16 + lm)*32 + quad*8);\
            _Pragma("unroll")                                                  \
            for (int ni = 0; ni < 4; ++ni)                                     \
                bF[ni] = *(const bf16x8*)(Bsb + (wc*64 + ni*16 + lm)*32 + quad*8);\
            _Pragma("unroll")                                                  \
            for (int mi = 0; mi < 2; ++mi)                                     \
                _Pragma("unroll")                                              \
                for (int ni = 0; ni < 4; ++ni)                                 \
                    acc[mi][ni] = __builtin_amdgcn_mfma_f32_16x16x32_bf16(     \
                        aF[mi], bF[ni], acc[mi][ni], 0, 0, 0);                 \
        }                                                                      \
    }

// blockIdx.x = n-tile (fastest -> A-strip L2 locality), blockIdx.y = m-tile
#define GEMM_PREAMBLE                                                          \
    __shared__ __attribute__((aligned(16))) unsigned short As[2][128 * 32];    \
    __shared__ __attribute__((aligned(16))) unsigned short Bs[2][128 * 32];    \
    const int tid  = threadIdx.x;                                              \
    const int lane = tid & 63;                                                 \
    const int w    = tid >> 6;          /* 0..7 */                             \
    const int wr   = w >> 1, wc = w & 1; /* 4x2 wave grid */                   \
    const int lm   = lane & 15, quad = lane >> 4;                              \
    const int n0   = blockIdx.x * 128, m0 = blockIdx.y * 128;                  \
    f32x4 acc[2][4] = {};

// ---- plain GEMM (MLP): C = act(A @ Bt^T + bias) ----
template <int EPI, int OUT_BF16, int NGUARD>
__global__ __launch_bounds__(512, 6)
void gemm_mfma(const unsigned short* __restrict__ A,
               const unsigned short* __restrict__ Bt,
               const float* __restrict__ bias,
               void* __restrict__ Cv, int ldc, int Nreal, int K)
{
    GEMM_PREAMBLE
    GEMM_CORE(A, Bt, K)
    #pragma unroll
    for (int mi = 0; mi < 2; ++mi)
        #pragma unroll
        for (int r = 0; r < 4; ++r) {
            const size_t row = m0 + wr * 32 + mi * 16 + quad * 4 + r;
            #pragma unroll
            for (int ni = 0; ni < 4; ++ni) {
                const int col = n0 + wc * 64 + ni * 16 + lm;
                if (!NGUARD || col < Nreal) {
                    float v = acc[mi][ni][r] + bias[col];
                    if (EPI == EPI_RELU) v = fmaxf(v, 0.f);
                    if (EPI == EPI_TANH) v = tanhfast(v);
                    if (OUT_BF16) ((unsigned short*)Cv)[row * ldc + col] = f2bf(v);
                    else          ((float*)Cv)[row * ldc + col] = v;
                }
            }
        }
}

// ---- LSTM GEMM: z = A @ Wt^T + biasI, gates fused in epilogue ----
// Wt cols interleaved: n' = (u>>4)*64 + g*16 + (u&15); wave's 64-col group
// (wc) holds all 4 gates of 16 units -> lane's 4 ni accs = (i,f,g,o).
__global__ __launch_bounds__(512, 6)
void gemm_lstm(const unsigned short* __restrict__ A,
               const unsigned short* __restrict__ Bt,
               const float* __restrict__ biasI,
               float* __restrict__ c,
               unsigned short* __restrict__ hdst, int ldh, int hoff,
               unsigned short* __restrict__ dec, int doff, int K)
{
    GEMM_PREAMBLE
    GEMM_CORE(A, Bt, K)
    const int u = ((n0 + wc * 64) >> 6) * 16 + lm;
    if (u >= 356) return;
    float bI[4];
    #pragma unroll
    for (int ni = 0; ni < 4; ++ni) bI[ni] = biasI[n0 + wc * 64 + ni * 16 + lm];
    #pragma unroll
    for (int mi = 0; mi < 2; ++mi)
        #pragma unroll
        for (int r = 0; r < 4; ++r) {
            const size_t row = m0 + wr * 32 + mi * 16 + quad * 4 + r;
            const float zi = acc[mi][0][r] + bI[0];
            const float zf = acc[mi][1][r] + bI[1];
            const float zg = acc[mi][2][r] + bI[2];
            const float zo = acc[mi][3][r] + bI[3];
            const size_t ci = row * 356 + u;
            const float cn = sigf(zf) * c[ci] + sigf(zi) * tanhfast(zg);
            c[ci] = cn;
            const unsigned short hb = f2bf(sigf(zo) * tanhfast(cn));
            if (hdst) hdst[row * (size_t)ldh + hoff + u] = hb;
            if (dec)  dec[row * (size_t)2496 + doff + u] = hb;
        }
}

// ---- LSTM weight pack (enc+dec in one launch; blockIdx.y selects) ----
struct PackArgs {
    const float *Wa0, *Wb0, *bias0; unsigned short* Wt0; float* bI0; int K10, K0, Kp0;
    const float *Wa1, *Wb1, *bias1; unsigned short* Wt1; float* bI1; int K11, K1, Kp1;
};
__global__ void pack_lstm2(PackArgs p)
{
    const float* Wa  = blockIdx.y ? p.Wa1  : p.Wa0;
    const float* Wb  = blockIdx.y ? p.Wb1  : p.Wb0;
    const float* bias= blockIdx.y ? p.bias1: p.bias0;
    unsigned short* Wt = blockIdx.y ? p.Wt1 : p.Wt0;
    float* biasI = blockIdx.y ? p.bI1 : p.bI0;
    const int K1 = blockIdx.y ? p.K11 : p.K10;
    const int K  = blockIdx.y ? p.K1  : p.K0;
    const int Kp = blockIdx.y ? p.Kp1 : p.Kp0;
    const int idx = blockIdx.x * 256 + threadIdx.x;
    if (idx >= 1536 * Kp) return;
    const int np = idx / Kp, k = idx - np * Kp;
    const int ub = np >> 6, g = (np >> 4) & 3, ul = np & 15;
    const int u = ub * 16 + ul;
    const bool valid = (u < 356);
    const int norig = g * 356 + u;
    float v = 0.f;
    if (valid && k < K)
        v = (k < K1) ? Wa[(size_t)k * 1424 + norig]
                     : Wb[(size_t)(k - K1) * 1424 + norig];
    Wt[(size_t)np * Kp + k] = f2bf(v);
    if (k == 0) biasI[np] = valid ? bias[norig] : 0.f;
}

// ---- MLP weight transpose+pack (fp32 [K][N] -> bf16 [Np][Kp]) ----
__global__ void transpose_pack(const float* __restrict__ W, int K, int N,
                               unsigned short* __restrict__ Wt, int Kp, int Np)
{
    __shared__ float t[32][33];
    const int n0 = blockIdx.x * 32, k0 = blockIdx.y * 32;
    const int tx = threadIdx.x, ty = threadIdx.y;
    #pragma unroll
    for (int r = 0; r < 4; ++r) {
        const int k = k0 + ty + 8 * r, n = n0 + tx;
        t[ty + 8 * r][tx] = (k < K && n < N) ? W[(size_t)k * N + n] : 0.f;
    }
    __syncthreads();
    #pragma unroll
    for (int r = 0; r < 4; ++r) {
        const int k = k0 + tx, n = n0 + ty + 8 * r;
        if (k < Kp && n < Np) Wt[(size_t)n * Kp + k] = f2bf(t[tx][ty + 8 * r]);
    }
}

// three 1024x1024 transposes in one launch (blockIdx.z selects)
struct WP3 { const float *s0, *s1, *s2; unsigned short *d0, *d1, *d2; };
__global__ void transpose_pack3(WP3 p)
{
    __shared__ float t[32][33];
    const float* W = (blockIdx.z == 0) ? p.s0 : (blockIdx.z == 1) ? p.s1 : p.s2;
    unsigned short* Wt = (blockIdx.z == 0) ? p.d0 : (blockIdx.z == 1) ? p.d1 : p.d2;
    const int n0 = blockIdx.x * 32, k0 = blockIdx.y * 32;
    const int tx = threadIdx.x, ty = threadIdx.y;
    #pragma unroll
    for (int r = 0; r < 4; ++r)
        t[ty + 8 * r][tx] = W[(size_t)(k0 + ty + 8 * r) * 1024 + n0 + tx];
    __syncthreads();
    #pragma unroll
    for (int r = 0; r < 4; ++r)
        Wt[(size_t)(n0 + ty + 8 * r) * 1024 + k0 + tx] = f2bf(t[tx][ty + 8 * r]);
}

// ---- targeted pad zeroing (16 MB instead of 140 MB of memsets) ----
__global__ void zero_pads(unsigned short* __restrict__ AcE,
                          unsigned short* __restrict__ AcD,
                          unsigned short* __restrict__ dcd,
                          unsigned short* __restrict__ cc)
{
    const size_t N0 = (size_t)8192 * 379, N1 = (size_t)6 * 8192 * 23;
    const size_t N2 = (size_t)8192 * 371, N3 = (size_t)6 * 8192 * 15;
    const size_t N4 = (size_t)8192 * 4,   N5 = (size_t)8192 * 356 * 2;
    size_t i = (size_t)blockIdx.x * 256 + threadIdx.x;
    if (i < N0) { const size_t r = i / 379; AcE[r * 448 + 69 + i % 379] = 0; return; }
    i -= N0;
    if (i < N1) { const size_t r = 8192 + i / 23; AcE[r * 448 + 425 + i % 23] = 0; return; }
    i -= N1;
    if (i < N2) { const size_t r = i / 371; AcD[r * 416 + 45 + i % 371] = 0; return; }
    i -= N2;
    if (i < N3) { const size_t r = 8192 + i / 15; AcD[r * 416 + 401 + i % 15] = 0; return; }
    i -= N3;
    if (i < N4) { dcd[(i / 4) * 2496 + 2492 + (i & 3)] = 0; return; }
    i -= N4;
    if (i < N5) cc[i] = 0;
}

// ---- fill x AND m time-slices into the per-step concat buffers (bf16) ----
__global__ void fill_slices2(const float* __restrict__ x,
                             const float* __restrict__ m,
                             unsigned short* __restrict__ AcE,
                             unsigned short* __restrict__ AcD)
{
    const int NX = 8192 * 7 * 69;
    int i = blockIdx.x * 256 + threadIdx.x;
    if (i < NX) {
        const int b = i / (7 * 69), rem = i - b * 7 * 69;
        const int t = rem / 69, f = rem - t * 69;
        AcE[(size_t)t * 8192 * 448 + (size_t)b * 448 + f] = f2bf(x[i]);
        return;
    }
    i -= NX;
    if (i < 8192 * 7 * 45) {
        const int b = i / (7 * 45), rem = i - b * 7 * 45;
        const int t = rem / 45, f = rem - t * 45;
        AcD[(size_t)t * 8192 * 416 + (size_t)b * 416 + f] = f2bf(m[i]);
    }
}

extern "C" void kernel_launch(void* const* d_in, const int* in_sizes, int n_in,
                              void* d_out, int out_size, void* d_ws, size_t ws_size,
                              hipStream_t stream)
{
    const float* x     = (const float*)d_in[0];
    const float* m     = (const float*)d_in[1];
    const float* enc_W = (const float*)d_in[2];
    const float* enc_U = (const float*)d_in[3];
    const float* enc_b = (const float*)d_in[4];
    const float* dec_W = (const float*)d_in[5];
    const float* dec_Um= (const float*)d_in[6];
    const float* dec_b = (const float*)d_in[7];
    const float* W_map = (const float*)d_in[8];
    const float* b_map = (const float*)d_in[9];
    const float* W1    = (const float*)d_in[10];
    const float* b1    = (const float*)d_in[11];
    const float* W2    = (const float*)d_in[12];
    const float* b2    = (const float*)d_in[13];
    const float* W3    = (const float*)d_in[14];
    const float* b3    = (const float*)d_in[15];
    const float* W_out = (const float*)d_in[16];
    const float* b_out = (const float*)d_in[17];
    float* out = (float*)d_out;

    const int B = 8192, T = 7, FE = 69, FD = 45;
    const int KE = 448, KD = 416, KMP = 2496;

    char* ws = (char*)d_ws;
    size_t off = 0;
    auto alloc = [&](size_t bytes) -> void* {
        void* p = ws + off; off = (off + bytes + 255) & ~(size_t)255; return p;
    };
    unsigned short* WtE = (unsigned short*)alloc((size_t)1536 * KE * 2);
    unsigned short* WtD = (unsigned short*)alloc((size_t)1536 * KD * 2);
    unsigned short* WtM = (unsigned short*)alloc((size_t)1024 * KMP * 2);
    unsigned short* Wt1 = (unsigned short*)alloc((size_t)1024 * 1024 * 2);
    unsigned short* Wt2 = (unsigned short*)alloc((size_t)1024 * 1024 * 2);
    unsigned short* Wt3 = (unsigned short*)alloc((size_t)1024 * 1024 * 2);
    unsigned short* WtO = (unsigned short*)alloc((size_t)256 * 1024 * 2);
    float* bIE = (float*)alloc(1536 * 4);
    float* bID = (float*)alloc(1536 * 4);
    unsigned short* AcE = (unsigned short*)alloc((size_t)T * B * KE * 2);
    unsigned short* AcD = (unsigned short*)alloc((size_t)T * B * KD * 2);
    unsigned short* dcd = (unsigned short*)alloc((size_t)B * KMP * 2);
    unsigned short* a1  = (unsigned short*)alloc((size_t)B * 1024 * 2);
    unsigned short* a2  = (unsigned short*)alloc((size_t)B * 1024 * 2);
    float* c = (float*)alloc((size_t)B * 356 * 4);

    // ---- weight packing ----
    PackArgs pa{enc_W, enc_U, enc_b, WtE, bIE, FE, FE + 356, KE,
                dec_W, dec_Um, dec_b, WtD, bID, FD, FD + 356, KD};
    pack_lstm2<<<dim3((1536 * KE + 255) / 256, 2), 256, 0, stream>>>(pa);
    const dim3 tb(32, 8);
    transpose_pack<<<dim3(1024 / 32, KMP / 32), tb, 0, stream>>>(
        W_map, 2492, 1024, WtM, KMP, 1024);
    WP3 p3{W1, W2, W3, Wt1, Wt2, Wt3};
    transpose_pack3<<<dim3(32, 32, 3), tb, 0, stream>>>(p3);
    transpose_pack<<<dim3(256 / 32, 1024 / 32), tb, 0, stream>>>(
        W_out, 1024, 168, WtO, 1024, 256);

    // ---- targeted zero: pads + t0 h-regions + c ----
    {
        const size_t tot = (size_t)8192 * 379 + (size_t)6 * 8192 * 23
                         + (size_t)8192 * 371 + (size_t)6 * 8192 * 15
                         + (size_t)8192 * 4   + (size_t)8192 * 356 * 2;
        zero_pads<<<(unsigned)((tot + 255) / 256), 256, 0, stream>>>(
            AcE, AcD, dcd, (unsigned short*)c);
    }
    fill_slices2<<<(B * T * (FE + FD) + 255) / 256, 256, 0, stream>>>(
        x, m, AcE, AcD);

    // ---- sequential LSTM chain: 14 fused GEMM launches (512 thr, n-fast) ----
    const dim3 gz(12, 64);
    for (int t = 0; t < T; ++t) {
        unsigned short* At = AcE + (size_t)t * B * KE;
        unsigned short* hdst = (t < 6) ? AcE + (size_t)(t + 1) * B * KE : AcD;
        gemm_lstm<<<gz, 512, 0, stream>>>(
            At, WtE, bIE, c, hdst, (t < 6) ? KE : KD, (t < 6) ? FE : FD,
            nullptr, 0, KE);
    }
    for (int t = 0; t < T; ++t) {
        unsigned short* At = AcD + (size_t)t * B * KD;
        unsigned short* hdst = (t < 6) ? AcD + (size_t)(t + 1) * B * KD : nullptr;
        gemm_lstm<<<gz, 512, 0, stream>>>(
            At, WtD, bID, c, hdst, KD, FD, dcd, t * 356, KD);
    }

    // ---- MLP head ----
    gemm_mfma<EPI_RELU, 1, 0><<<dim3(8, 64), 512, 0, stream>>>(
        dcd, WtM, b_map, a1, 1024, 1024, KMP);
    gemm_mfma<EPI_TANH, 1, 0><<<dim3(8, 64), 512, 0, stream>>>(
        a1, Wt1, b1, a2, 1024, 1024, 1024);
    gemm_mfma<EPI_TANH, 1, 0><<<dim3(8, 64), 512, 0, stream>>>(
        a2, Wt2, b2, a1, 1024, 1024, 1024);
    gemm_mfma<EPI_TANH, 1, 0><<<dim3(8, 64), 512, 0, stream>>>(
        a1, Wt3, b3, a2, 1024, 1024, 1024);
    gemm_mfma<EPI_NONE, 0, 1><<<dim3(2, 64), 512, 0, stream>>>(
        a2, WtO, b_out, out, 168, 168, 1024);
}

// Round 9
// 601.126 us; speedup vs baseline: 1.1908x; 1.1908x over previous
//
#include <hip/hip_runtime.h>
#include <math.h>

// ---------------------------------------------------------------------------
// Round 9: r8's 512-thread / 8-wave blocks (2x4 acc per wave, 128x128 tile,
// single-barrier double-buffered K-loop) + r7's m-fastest grid order
// (m0 = blockIdx.x). r8's n-fastest grid quadrupled HBM FETCH (40->162 MB,
// L3 streaming locality lost) and went memory-bound — only the grid order
// is reverted here.
// ---------------------------------------------------------------------------

using bf16x8 = __attribute__((ext_vector_type(8))) short;
using f32x4  = __attribute__((ext_vector_type(4))) float;

enum { EPI_NONE = 0, EPI_RELU = 1, EPI_TANH = 2 };

__device__ inline unsigned short f2bf(float f) {
    union { float f; unsigned u; } v; v.f = f;
    unsigned r = v.u + 0x7FFFu + ((v.u >> 16) & 1u);
    return (unsigned short)(r >> 16);
}
__device__ inline float sigf(float x) {
    return __fdividef(1.f, 1.f + __expf(-x));
}
__device__ inline float tanhfast(float x) {
    return 1.f - __fdividef(2.f, 1.f + __expf(2.f * x));
}

__device__ inline void gll16(const void* g, void* l) {
    __builtin_amdgcn_global_load_lds(
        (const __attribute__((address_space(1))) unsigned int*)(uintptr_t)g,
        (__attribute__((address_space(3))) unsigned int*)(unsigned int)(uintptr_t)l,
        16, 0, 0);
}

// stage one 128x32 A-tile + B-tile into buffer b_ (async; 1 chunk/thread)
#define STAGE(A_, Bt_, K_, k0_, b_)                                            \
    {                                                                          \
        const int row = tid >> 2, kc = tid & 3;                                \
        gll16((A_)  + (size_t)(m0 + row) * (K_) + (k0_) + kc * 8,              \
              (void*)&As[b_][tid * 8]);                                        \
        gll16((Bt_) + (size_t)(n0 + row) * (K_) + (k0_) + kc * 8,              \
              (void*)&Bs[b_][tid * 8]);                                        \
    }

// double-buffered K-loop: one barrier/iter, vmcnt drain overlapped with MFMA
#define GEMM_CORE(A_, Bt_, K_)                                                 \
    STAGE(A_, Bt_, K_, 0, 0)                                                   \
    {                                                                          \
        const int niter = (K_) / 32;                                           \
        for (int it = 0; it < niter; ++it) {                                   \
            __syncthreads();                                                   \
            if (it + 1 < niter) {                                              \
                const int kn = (it + 1) * 32, bn = (it + 1) & 1;               \
                STAGE(A_, Bt_, K_, kn, bn)                                     \
            }                                                                  \
            const unsigned short* Asb = As[it & 1];                            \
            const unsigned short* Bsb = Bs[it & 1];                            \
            bf16x8 aF[2], bF[4];                                               \
            _Pragma("unroll")                                                  \
            for (int mi = 0; mi < 2; ++mi)                                     \
                aF[mi] = *(const bf16x8*)(Asb + (wr*32 + mi*16 + lm)*32 + quad*8);\
            _Pragma("unroll")                                                  \
            for (int ni = 0; ni < 4; ++ni)                                     \
                bF[ni] = *(const bf16x8*)(Bsb + (wc*64 + ni*16 + lm)*32 + quad*8);\
            _Pragma("unroll")                                                  \
            for (int mi = 0; mi < 2; ++mi)                                     \
                _Pragma("unroll")                                              \
                for (int ni = 0; ni < 4; ++ni)                                 \
                    acc[mi][ni] = __builtin_amdgcn_mfma_f32_16x16x32_bf16(     \
                        aF[mi], bF[ni], acc[mi][ni], 0, 0, 0);                 \
        }                                                                      \
    }

// m-fastest: blockIdx.x = m-tile (consecutive blocks share the B-strip and
// stream A once; L3 absorbs n-tile re-reads -> FETCH ~= |A|)
#define GEMM_PREAMBLE                                                          \
    __shared__ __attribute__((aligned(16))) unsigned short As[2][128 * 32];    \
    __shared__ __attribute__((aligned(16))) unsigned short Bs[2][128 * 32];    \
    const int tid  = threadIdx.x;                                              \
    const int lane = tid & 63;                                                 \
    const int w    = tid >> 6;          /* 0..7 */                             \
    const int wr   = w >> 1, wc = w & 1; /* 4x2 wave grid */                   \
    const int lm   = lane & 15, quad = lane >> 4;                              \
    const int m0   = blockIdx.x * 128, n0 = blockIdx.y * 128;                  \
    f32x4 acc[2][4] = {};

// ---- plain GEMM (MLP): C = act(A @ Bt^T + bias) ----
template <int EPI, int OUT_BF16, int NGUARD>
__global__ __launch_bounds__(512, 6)
void gemm_mfma(const unsigned short* __restrict__ A,
               const unsigned short* __restrict__ Bt,
               const float* __restrict__ bias,
               void* __restrict__ Cv, int ldc, int Nreal, int K)
{
    GEMM_PREAMBLE
    GEMM_CORE(A, Bt, K)
    #pragma unroll
    for (int mi = 0; mi < 2; ++mi)
        #pragma unroll
        for (int r = 0; r < 4; ++r) {
            const size_t row = m0 + wr * 32 + mi * 16 + quad * 4 + r;
            #pragma unroll
            for (int ni = 0; ni < 4; ++ni) {
                const int col = n0 + wc * 64 + ni * 16 + lm;
                if (!NGUARD || col < Nreal) {
                    float v = acc[mi][ni][r] + bias[col];
                    if (EPI == EPI_RELU) v = fmaxf(v, 0.f);
                    if (EPI == EPI_TANH) v = tanhfast(v);
                    if (OUT_BF16) ((unsigned short*)Cv)[row * ldc + col] = f2bf(v);
                    else          ((float*)Cv)[row * ldc + col] = v;
                }
            }
        }
}

// ---- LSTM GEMM: z = A @ Wt^T + biasI, gates fused in epilogue ----
// Wt cols interleaved: n' = (u>>4)*64 + g*16 + (u&15); wave's 64-col group
// (wc) holds all 4 gates of 16 units -> lane's 4 ni accs = (i,f,g,o).
__global__ __launch_bounds__(512, 6)
void gemm_lstm(const unsigned short* __restrict__ A,
               const unsigned short* __restrict__ Bt,
               const float* __restrict__ biasI,
               float* __restrict__ c,
               unsigned short* __restrict__ hdst, int ldh, int hoff,
               unsigned short* __restrict__ dec, int doff, int K)
{
    GEMM_PREAMBLE
    GEMM_CORE(A, Bt, K)
    const int u = ((n0 + wc * 64) >> 6) * 16 + lm;
    if (u >= 356) return;
    float bI[4];
    #pragma unroll
    for (int ni = 0; ni < 4; ++ni) bI[ni] = biasI[n0 + wc * 64 + ni * 16 + lm];
    #pragma unroll
    for (int mi = 0; mi < 2; ++mi)
        #pragma unroll
        for (int r = 0; r < 4; ++r) {
            const size_t row = m0 + wr * 32 + mi * 16 + quad * 4 + r;
            const float zi = acc[mi][0][r] + bI[0];
            const float zf = acc[mi][1][r] + bI[1];
            const float zg = acc[mi][2][r] + bI[2];
            const float zo = acc[mi][3][r] + bI[3];
            const size_t ci = row * 356 + u;
            const float cn = sigf(zf) * c[ci] + sigf(zi) * tanhfast(zg);
            c[ci] = cn;
            const unsigned short hb = f2bf(sigf(zo) * tanhfast(cn));
            if (hdst) hdst[row * (size_t)ldh + hoff + u] = hb;
            if (dec)  dec[row * (size_t)2496 + doff + u] = hb;
        }
}

// ---- LSTM weight pack (enc+dec in one launch; blockIdx.y selects) ----
struct PackArgs {
    const float *Wa0, *Wb0, *bias0; unsigned short* Wt0; float* bI0; int K10, K0, Kp0;
    const float *Wa1, *Wb1, *bias1; unsigned short* Wt1; float* bI1; int K11, K1, Kp1;
};
__global__ void pack_lstm2(PackArgs p)
{
    const float* Wa  = blockIdx.y ? p.Wa1  : p.Wa0;
    const float* Wb  = blockIdx.y ? p.Wb1  : p.Wb0;
    const float* bias= blockIdx.y ? p.bias1: p.bias0;
    unsigned short* Wt = blockIdx.y ? p.Wt1 : p.Wt0;
    float* biasI = blockIdx.y ? p.bI1 : p.bI0;
    const int K1 = blockIdx.y ? p.K11 : p.K10;
    const int K  = blockIdx.y ? p.K1  : p.K0;
    const int Kp = blockIdx.y ? p.Kp1 : p.Kp0;
    const int idx = blockIdx.x * 256 + threadIdx.x;
    if (idx >= 1536 * Kp) return;
    const int np = idx / Kp, k = idx - np * Kp;
    const int ub = np >> 6, g = (np >> 4) & 3, ul = np & 15;
    const int u = ub * 16 + ul;
    const bool valid = (u < 356);
    const int norig = g * 356 + u;
    float v = 0.f;
    if (valid && k < K)
        v = (k < K1) ? Wa[(size_t)k * 1424 + norig]
                     : Wb[(size_t)(k - K1) * 1424 + norig];
    Wt[(size_t)np * Kp + k] = f2bf(v);
    if (k == 0) biasI[np] = valid ? bias[norig] : 0.f;
}

// ---- MLP weight transpose+pack (fp32 [K][N] -> bf16 [Np][Kp]) ----
__global__ void transpose_pack(const float* __restrict__ W, int K, int N,
                               unsigned short* __restrict__ Wt, int Kp, int Np)
{
    __shared__ float t[32][33];
    const int n0 = blockIdx.x * 32, k0 = blockIdx.y * 32;
    const int tx = threadIdx.x, ty = threadIdx.y;
    #pragma unroll
    for (int r = 0; r < 4; ++r) {
        const int k = k0 + ty + 8 * r, n = n0 + tx;
        t[ty + 8 * r][tx] = (k < K && n < N) ? W[(size_t)k * N + n] : 0.f;
    }
    __syncthreads();
    #pragma unroll
    for (int r = 0; r < 4; ++r) {
        const int k = k0 + tx, n = n0 + ty + 8 * r;
        if (k < Kp && n < Np) Wt[(size_t)n * Kp + k] = f2bf(t[tx][ty + 8 * r]);
    }
}

// three 1024x1024 transposes in one launch (blockIdx.z selects)
struct WP3 { const float *s0, *s1, *s2; unsigned short *d0, *d1, *d2; };
__global__ void transpose_pack3(WP3 p)
{
    __shared__ float t[32][33];
    const float* W = (blockIdx.z == 0) ? p.s0 : (blockIdx.z == 1) ? p.s1 : p.s2;
    unsigned short* Wt = (blockIdx.z == 0) ? p.d0 : (blockIdx.z == 1) ? p.d1 : p.d2;
    const int n0 = blockIdx.x * 32, k0 = blockIdx.y * 32;
    const int tx = threadIdx.x, ty = threadIdx.y;
    #pragma unroll
    for (int r = 0; r < 4; ++r)
        t[ty + 8 * r][tx] = W[(size_t)(k0 + ty + 8 * r) * 1024 + n0 + tx];
    __syncthreads();
    #pragma unroll
    for (int r = 0; r < 4; ++r)
        Wt[(size_t)(n0 + ty + 8 * r) * 1024 + k0 + tx] = f2bf(t[tx][ty + 8 * r]);
}

// ---- targeted pad zeroing (16 MB instead of 140 MB of memsets) ----
__global__ void zero_pads(unsigned short* __restrict__ AcE,
                          unsigned short* __restrict__ AcD,
                          unsigned short* __restrict__ dcd,
                          unsigned short* __restrict__ cc)
{
    const size_t N0 = (size_t)8192 * 379, N1 = (size_t)6 * 8192 * 23;
    const size_t N2 = (size_t)8192 * 371, N3 = (size_t)6 * 8192 * 15;
    const size_t N4 = (size_t)8192 * 4,   N5 = (size_t)8192 * 356 * 2;
    size_t i = (size_t)blockIdx.x * 256 + threadIdx.x;
    if (i < N0) { const size_t r = i / 379; AcE[r * 448 + 69 + i % 379] = 0; return; }
    i -= N0;
    if (i < N1) { const size_t r = 8192 + i / 23; AcE[r * 448 + 425 + i % 23] = 0; return; }
    i -= N1;
    if (i < N2) { const size_t r = i / 371; AcD[r * 416 + 45 + i % 371] = 0; return; }
    i -= N2;
    if (i < N3) { const size_t r = 8192 + i / 15; AcD[r * 416 + 401 + i % 15] = 0; return; }
    i -= N3;
    if (i < N4) { dcd[(i / 4) * 2496 + 2492 + (i & 3)] = 0; return; }
    i -= N4;
    if (i < N5) cc[i] = 0;
}

// ---- fill x AND m time-slices into the per-step concat buffers (bf16) ----
__global__ void fill_slices2(const float* __restrict__ x,
                             const float* __restrict__ m,
                             unsigned short* __restrict__ AcE,
                             unsigned short* __restrict__ AcD)
{
    const int NX = 8192 * 7 * 69;
    int i = blockIdx.x * 256 + threadIdx.x;
    if (i < NX) {
        const int b = i / (7 * 69), rem = i - b * 7 * 69;
        const int t = rem / 69, f = rem - t * 69;
        AcE[(size_t)t * 8192 * 448 + (size_t)b * 448 + f] = f2bf(x[i]);
        return;
    }
    i -= NX;
    if (i < 8192 * 7 * 45) {
        const int b = i / (7 * 45), rem = i - b * 7 * 45;
        const int t = rem / 45, f = rem - t * 45;
        AcD[(size_t)t * 8192 * 416 + (size_t)b * 416 + f] = f2bf(m[i]);
    }
}

extern "C" void kernel_launch(void* const* d_in, const int* in_sizes, int n_in,
                              void* d_out, int out_size, void* d_ws, size_t ws_size,
                              hipStream_t stream)
{
    const float* x     = (const float*)d_in[0];
    const float* m     = (const float*)d_in[1];
    const float* enc_W = (const float*)d_in[2];
    const float* enc_U = (const float*)d_in[3];
    const float* enc_b = (const float*)d_in[4];
    const float* dec_W = (const float*)d_in[5];
    const float* dec_Um= (const float*)d_in[6];
    const float* dec_b = (const float*)d_in[7];
    const float* W_map = (const float*)d_in[8];
    const float* b_map = (const float*)d_in[9];
    const float* W1    = (const float*)d_in[10];
    const float* b1    = (const float*)d_in[11];
    const float* W2    = (const float*)d_in[12];
    const float* b2    = (const float*)d_in[13];
    const float* W3    = (const float*)d_in[14];
    const float* b3    = (const float*)d_in[15];
    const float* W_out = (const float*)d_in[16];
    const float* b_out = (const float*)d_in[17];
    float* out = (float*)d_out;

    const int B = 8192, T = 7, FE = 69, FD = 45;
    const int KE = 448, KD = 416, KMP = 2496;

    char* ws = (char*)d_ws;
    size_t off = 0;
    auto alloc = [&](size_t bytes) -> void* {
        void* p = ws + off; off = (off + bytes + 255) & ~(size_t)255; return p;
    };
    unsigned short* WtE = (unsigned short*)alloc((size_t)1536 * KE * 2);
    unsigned short* WtD = (unsigned short*)alloc((size_t)1536 * KD * 2);
    unsigned short* WtM = (unsigned short*)alloc((size_t)1024 * KMP * 2);
    unsigned short* Wt1 = (unsigned short*)alloc((size_t)1024 * 1024 * 2);
    unsigned short* Wt2 = (unsigned short*)alloc((size_t)1024 * 1024 * 2);
    unsigned short* Wt3 = (unsigned short*)alloc((size_t)1024 * 1024 * 2);
    unsigned short* WtO = (unsigned short*)alloc((size_t)256 * 1024 * 2);
    float* bIE = (float*)alloc(1536 * 4);
    float* bID = (float*)alloc(1536 * 4);
    unsigned short* AcE = (unsigned short*)alloc((size_t)T * B * KE * 2);
    unsigned short* AcD = (unsigned short*)alloc((size_t)T * B * KD * 2);
    unsigned short* dcd = (unsigned short*)alloc((size_t)B * KMP * 2);
    unsigned short* a1  = (unsigned short*)alloc((size_t)B * 1024 * 2);
    unsigned short* a2  = (unsigned short*)alloc((size_t)B * 1024 * 2);
    float* c = (float*)alloc((size_t)B * 356 * 4);

    // ---- weight packing ----
    PackArgs pa{enc_W, enc_U, enc_b, WtE, bIE, FE, FE + 356, KE,
                dec_W, dec_Um, dec_b, WtD, bID, FD, FD + 356, KD};
    pack_lstm2<<<dim3((1536 * KE + 255) / 256, 2), 256, 0, stream>>>(pa);
    const dim3 tb(32, 8);
    transpose_pack<<<dim3(1024 / 32, KMP / 32), tb, 0, stream>>>(
        W_map, 2492, 1024, WtM, KMP, 1024);
    WP3 p3{W1, W2, W3, Wt1, Wt2, Wt3};
    transpose_pack3<<<dim3(32, 32, 3), tb, 0, stream>>>(p3);
    transpose_pack<<<dim3(256 / 32, 1024 / 32), tb, 0, stream>>>(
        W_out, 1024, 168, WtO, 1024, 256);

    // ---- targeted zero: pads + t0 h-regions + c ----
    {
        const size_t tot = (size_t)8192 * 379 + (size_t)6 * 8192 * 23
                         + (size_t)8192 * 371 + (size_t)6 * 8192 * 15
                         + (size_t)8192 * 4   + (size_t)8192 * 356 * 2;
        zero_pads<<<(unsigned)((tot + 255) / 256), 256, 0, stream>>>(
            AcE, AcD, dcd, (unsigned short*)c);
    }
    fill_slices2<<<(B * T * (FE + FD) + 255) / 256, 256, 0, stream>>>(
        x, m, AcE, AcD);

    // ---- sequential LSTM chain: 14 fused GEMM launches (512 thr, m-fast) ----
    const dim3 gz(64, 12);
    for (int t = 0; t < T; ++t) {
        unsigned short* At = AcE + (size_t)t * B * KE;
        unsigned short* hdst = (t < 6) ? AcE + (size_t)(t + 1) * B * KE : AcD;
        gemm_lstm<<<gz, 512, 0, stream>>>(
            At, WtE, bIE, c, hdst, (t < 6) ? KE : KD, (t < 6) ? FE : FD,
            nullptr, 0, KE);
    }
    for (int t = 0; t < T; ++t) {
        unsigned short* At = AcD + (size_t)t * B * KD;
        unsigned short* hdst = (t < 6) ? AcD + (size_t)(t + 1) * B * KD : nullptr;
        gemm_lstm<<<gz, 512, 0, stream>>>(
            At, WtD, bID, c, hdst, KD, FD, dcd, t * 356, KD);
    }

    // ---- MLP head ----
    gemm_mfma<EPI_RELU, 1, 0><<<dim3(64, 8), 512, 0, stream>>>(
        dcd, WtM, b_map, a1, 1024, 1024, KMP);
    gemm_mfma<EPI_TANH, 1, 0><<<dim3(64, 8), 512, 0, stream>>>(
        a1, Wt1, b1, a2, 1024, 1024, 1024);
    gemm_mfma<EPI_TANH, 1, 0><<<dim3(64, 8), 512, 0, stream>>>(
        a2, Wt2, b2, a1, 1024, 1024, 1024);
    gemm_mfma<EPI_TANH, 1, 0><<<dim3(64, 8), 512, 0, stream>>>(
        a1, Wt3, b3, a2, 1024, 1024, 1024);
    gemm_mfma<EPI_NONE, 0, 1><<<dim3(64, 2), 512, 0, stream>>>(
        a2, WtO, b_out, out, 168, 168, 1024);
}